// Round 1
// baseline (325.707 us; speedup 1.0000x reference)
//
#include <hip/hip_runtime.h>
#include <hip/hip_bf16.h>

// EmbeddingBag mode='sum':
//   W       : [TABLE_LEN=1e6, EMB=64] float32
//   indices : [N_IDX=819200] int32
//   offsets : [N_BAGS=16384] int32 (start of each bag; last bag ends at N_IDX)
//   out     : [N_BAGS, 64] float32,  out[b] = sum_{i in bag b} W[indices[i]]
//
// Strategy: one wave (64 lanes) per bag; lane = column. Each gathered row is
// one coalesced 256B wave load. Indices loaded once per 64-chunk with a single
// per-lane load, then broadcast with __shfl. 4-way unroll / 4 accumulators for
// memory-level parallelism.

#define EMB 64

__global__ __launch_bounds__(256) void embag_sum_kernel(
    const float* __restrict__ W,
    const int* __restrict__ indices,
    const int* __restrict__ offsets,
    float* __restrict__ out,
    int n_bags, int n_idx)
{
    const int wave = (int)((blockIdx.x * blockDim.x + threadIdx.x) >> 6);
    const int lane = (int)(threadIdx.x & 63);
    if (wave >= n_bags) return;

    const int start = offsets[wave];
    const int end   = (wave + 1 < n_bags) ? offsets[wave + 1] : n_idx;

    float acc0 = 0.f, acc1 = 0.f, acc2 = 0.f, acc3 = 0.f;

    for (int base = start; base < end; base += 64) {
        const int rem = end - base;
        const int cnt = rem < 64 ? rem : 64;
        // one coalesced vector load of up to 64 indices for this chunk
        const int myIdx = (lane < cnt) ? indices[base + lane] : 0;

        int k = 0;
        for (; k + 3 < cnt; k += 4) {
            const unsigned i0 = (unsigned)__shfl(myIdx, k,     64);
            const unsigned i1 = (unsigned)__shfl(myIdx, k + 1, 64);
            const unsigned i2 = (unsigned)__shfl(myIdx, k + 2, 64);
            const unsigned i3 = (unsigned)__shfl(myIdx, k + 3, 64);
            // 4 independent coalesced 256B row loads in flight
            const float w0 = W[i0 * EMB + lane];
            const float w1 = W[i1 * EMB + lane];
            const float w2 = W[i2 * EMB + lane];
            const float w3 = W[i3 * EMB + lane];
            acc0 += w0; acc1 += w1; acc2 += w2; acc3 += w3;
        }
        for (; k < cnt; ++k) {
            const unsigned i = (unsigned)__shfl(myIdx, k, 64);
            acc0 += W[i * EMB + lane];
        }
    }

    out[(unsigned)wave * EMB + lane] = (acc0 + acc1) + (acc2 + acc3);
}

extern "C" void kernel_launch(void* const* d_in, const int* in_sizes, int n_in,
                              void* d_out, int out_size, void* d_ws, size_t ws_size,
                              hipStream_t stream) {
    const float* W        = (const float*)d_in[0];
    const int*   indices  = (const int*)d_in[1];
    const int*   offsets  = (const int*)d_in[2];
    float*       out      = (float*)d_out;

    const int n_idx  = in_sizes[1];
    const int n_bags = in_sizes[2];

    // one wave per bag; 4 waves per 256-thread block
    const int waves_per_block = 256 / 64;
    const int n_blocks = (n_bags + waves_per_block - 1) / waves_per_block;

    embag_sum_kernel<<<n_blocks, 256, 0, stream>>>(W, indices, offsets, out,
                                                   n_bags, n_idx);
}